// Round 1
// 1668.681 us; speedup vs baseline: 1.0442x; 1.0442x over previous
//
#include <hip/hip_runtime.h>
#include <math.h>

#define N_NODES 100000
#define N_NNZ   1000000
#define F_IN    1433
#define F_HID   128
#define F_OUT   64
#define N_POS   20000
#define N_NEG   20000
#define EPS_PN  1e-6f
#define NPART   2048        // spmm grid / colsum partial count

typedef float f32x2   __attribute__((ext_vector_type(2)));
typedef float f32x4   __attribute__((ext_vector_type(4)));
typedef float f32x4u  __attribute__((ext_vector_type(4), aligned(4)));
typedef short bf16x8  __attribute__((ext_vector_type(8)));
typedef short bf16x4  __attribute__((ext_vector_type(4)));

__device__ inline short f2bf(float f) {
  union { float f; unsigned u; } x; x.f = f;
  unsigned r = x.u + 0x7fff + ((x.u >> 16) & 1);   // round-to-nearest-even
  return (short)(r >> 16);
}

// ---- W cast+transpose: Wt[n][k] (bf16, Kp-padded) from W[k][n] fp32 --------
__global__ __launch_bounds__(256) void wcast_kernel(
    const float* __restrict__ W, short* __restrict__ Wt, int K, int Kp, int N) {
  int idx = blockIdx.x * blockDim.x + threadIdx.x;
  if (idx >= N * Kp) return;
  int n = idx / Kp, k = idx - n * Kp;
  float v = (k < K) ? W[(long long)k * N + n] : 0.0f;
  Wt[idx] = f2bf(v);
}

// ---- MFMA GEMM, register-prefetch double buffering -------------------------
// C[M,N] = A[M,K] fp32 @ Wt^T (bf16). 4 waves/block arranged WM x WN;
// per-wave tile (MI*16) x (NJ*16).
template<int BMt, int BNt, int WM, int WN>
__global__ __launch_bounds__(256) void mfma_gemm(
    const float* __restrict__ A, const short* __restrict__ Wt,
    float* __restrict__ C, int M, int K, int Kp, int N) {
  constexpr int LD  = 40;                      // LDS row stride in shorts
  constexpr int MI  = BMt / (WM * 16);
  constexpr int NJ  = BNt / (WN * 16);
  constexpr int APF = (BMt * 32) / (256 * 4);  // f32x4 loads of A per thread
  constexpr int WPF = (BNt * 32) / (256 * 8);  // bf16x8 loads of W per thread
  __shared__ __align__(16) short As[BMt * LD];
  __shared__ __align__(16) short Ws[BNt * LD];
  int tid = threadIdx.x;
  int lane = tid & 63, w = tid >> 6;
  int wm = w % WM, wn = w / WM;
  int row0 = blockIdx.x * BMt;
  int ml = lane & 15, kgrp = lane >> 4;

  f32x4 acc[MI][NJ] = {};
  f32x4 pa[APF];
  bf16x8 pw[WPF];

  auto load_a = [&](int k0, f32x4* dst) {
#pragma unroll
    for (int q = 0; q < APF; ++q) {
      int idx = tid + q * 256;
      int r = idx >> 3, k4 = (idx & 7) * 4;
      int gr = row0 + r, gk = k0 + k4;
      f32x4 v = {0.f, 0.f, 0.f, 0.f};
      if (gr < M) {
        if (gk + 3 < K) v = *(const f32x4u*)&A[(long long)gr * K + gk];
        else {
#pragma unroll
          for (int i = 0; i < 4; ++i)
            if (gk + i < K) v[i] = A[(long long)gr * K + gk + i];
        }
      }
      dst[q] = v;
    }
  };
  auto load_w = [&](int k0, bf16x8* dst) {
#pragma unroll
    for (int q = 0; q < WPF; ++q) {
      int idx = tid + q * 256;
      int n = idx >> 2, kk8 = (idx & 3) * 8;
      dst[q] = *(const bf16x8*)&Wt[(long long)n * Kp + k0 + kk8];
    }
  };

  load_a(0, pa);
  load_w(0, pw);

  for (int k0 = 0; k0 < Kp; k0 += 32) {
#pragma unroll
    for (int q = 0; q < APF; ++q) {
      int idx = tid + q * 256;
      int r = idx >> 3, k4 = (idx & 7) * 4;
      bf16x4 b;
#pragma unroll
      for (int i = 0; i < 4; ++i) b[i] = f2bf(pa[q][i]);
      *(bf16x4*)&As[r * LD + k4] = b;
    }
#pragma unroll
    for (int q = 0; q < WPF; ++q) {
      int idx = tid + q * 256;
      int n = idx >> 2, kk8 = (idx & 3) * 8;
      *(bf16x8*)&Ws[n * LD + kk8] = pw[q];
    }
    __syncthreads();

    if (k0 + 32 < Kp) {           // prefetch next tile during MFMAs
      load_a(k0 + 32, pa);
      load_w(k0 + 32, pw);
    }

    bf16x8 af[MI], bfr[NJ];
#pragma unroll
    for (int i = 0; i < MI; ++i)
      af[i] = *(const bf16x8*)&As[(wm * MI * 16 + i * 16 + ml) * LD + kgrp * 8];
#pragma unroll
    for (int j = 0; j < NJ; ++j)
      bfr[j] = *(const bf16x8*)&Ws[(wn * NJ * 16 + j * 16 + ml) * LD + kgrp * 8];
#pragma unroll
    for (int i = 0; i < MI; ++i)
#pragma unroll
      for (int j = 0; j < NJ; ++j)
        acc[i][j] = __builtin_amdgcn_mfma_f32_16x16x32_bf16(
            af[i], bfr[j], acc[i][j], 0, 0, 0);
    __syncthreads();
  }

  // epilogue: D mapping col = lane&15, row = (lane>>4)*4 + rr
#pragma unroll
  for (int i = 0; i < MI; ++i)
#pragma unroll
    for (int j = 0; j < NJ; ++j)
#pragma unroll
      for (int rr = 0; rr < 4; ++rr) {
        int gr = row0 + wm * MI * 16 + i * 16 + kgrp * 4 + rr;
        int gc = wn * NJ * 16 + j * 16 + ml;
        if (gr < M) C[(long long)gr * N + gc] = acc[i][j][rr];
      }
}

// ---------------- CSR build -------------------------------------------------
__global__ __launch_bounds__(256) void hist_kernel(
    const int* __restrict__ row, int* __restrict__ cnt, int nnz) {
  int i = blockIdx.x * blockDim.x + threadIdx.x;
  if (i < nnz) atomicAdd(&cnt[row[i]], 1);
}

__global__ __launch_bounds__(1024) void scan_kernel(
    const int* __restrict__ cnt, int* __restrict__ row_ptr,
    int* __restrict__ cursor, int n, int nnz) {
  __shared__ int part[1024];
  int t = threadIdx.x;
  int chunk = (n + 1023) >> 10;
  int s0 = t * chunk, s1 = s0 + chunk; if (s1 > n) s1 = n; if (s0 > n) s0 = n;
  int s = 0;
  for (int i = s0; i < s1; ++i) s += cnt[i];
  part[t] = s;
  __syncthreads();
  for (int off = 1; off < 1024; off <<= 1) {
    int v = (t >= off) ? part[t - off] : 0;
    __syncthreads();
    part[t] += v;
    __syncthreads();
  }
  int run = part[t] - s;                      // exclusive prefix
  for (int i = s0; i < s1; ++i) {
    row_ptr[i] = run; cursor[i] = run;
    run += cnt[i];
  }
  if (t == 0) row_ptr[n] = nnz;
}

__global__ __launch_bounds__(256) void scatter_kernel(
    const int* __restrict__ row, const int* __restrict__ col,
    const float* __restrict__ val, int* __restrict__ cursor,
    int* __restrict__ scol, float* __restrict__ sval, int nnz) {
  int i = blockIdx.x * blockDim.x + threadIdx.x;
  if (i >= nnz) return;
  int p = atomicAdd(&cursor[row[i]], 1);
  scol[p] = col[i];
  sval[p] = val[i];
}

// ---- CSR SpMM fused bias+relu+colsum-partial, F=128 ------------------------
// grid-stride over rows, one wave per row, lane owns feats {2l, 2l+1}.
// Per-block column-sum partial accumulated in registers (lane's feature
// indices are fixed), LDS-reduced across the 4 waves, one partial row per
// block -> no global atomics at all.
__global__ __launch_bounds__(256) void spmm128_fused_kernel(
    const int* __restrict__ rp, const int* __restrict__ scol,
    const float* __restrict__ sval, const float* __restrict__ sup,
    const float* __restrict__ bias, float* __restrict__ z,
    float* __restrict__ part, int M) {
  int w = threadIdx.x >> 6, lane = threadIdx.x & 63;
  f32x2 b = *(const f32x2*)&bias[2 * lane];
  f32x2 cs = {0.f, 0.f};
  for (int r = blockIdx.x * 4 + w; r < M; r += gridDim.x * 4) {
    int j0 = rp[r], j1 = rp[r + 1];
    f32x2 a = {0.f, 0.f};
    int j = j0;
    for (; j + 4 <= j1; j += 4) {       // 4 gathers in flight
      int   c0 = scol[j],     c1 = scol[j + 1];
      int   c2 = scol[j + 2], c3 = scol[j + 3];
      float v0 = sval[j],     v1 = sval[j + 1];
      float v2 = sval[j + 2], v3 = sval[j + 3];
      f32x2 s0 = *(const f32x2*)&sup[(long long)c0 * 128 + 2 * lane];
      f32x2 s1 = *(const f32x2*)&sup[(long long)c1 * 128 + 2 * lane];
      f32x2 s2 = *(const f32x2*)&sup[(long long)c2 * 128 + 2 * lane];
      f32x2 s3 = *(const f32x2*)&sup[(long long)c3 * 128 + 2 * lane];
      a.x += v0 * s0.x + v1 * s1.x + v2 * s2.x + v3 * s3.x;
      a.y += v0 * s0.y + v1 * s1.y + v2 * s2.y + v3 * s3.y;
    }
    for (; j < j1; ++j) {
      int c = scol[j];
      float v = sval[j];
      f32x2 s = *(const f32x2*)&sup[(long long)c * 128 + 2 * lane];
      a.x += v * s.x;
      a.y += v * s.y;
    }
    f32x2 zz;
    zz.x = a.x + b.x; zz.x = zz.x > 0.f ? zz.x : 0.f;
    zz.y = a.y + b.y; zz.y = zz.y > 0.f ? zz.y : 0.f;
    cs.x += zz.x; cs.y += zz.y;
    *(f32x2*)&z[(long long)r * 128 + 2 * lane] = zz;
  }
  __shared__ f32x2 red[4][64];
  red[w][lane] = cs;
  __syncthreads();
  if (w == 0) {
    f32x2 t0 = red[0][lane], t1 = red[1][lane];
    f32x2 t2 = red[2][lane], t3 = red[3][lane];
    f32x2 t;
    t.x = t0.x + t1.x + t2.x + t3.x;
    t.y = t0.y + t1.y + t2.y + t3.y;
    *(f32x2*)&part[(long long)blockIdx.x * 128 + 2 * lane] = t;
  }
}

// ---- CSR SpMM fused bias+relu+colsum-partial, F=64 -------------------------
__global__ __launch_bounds__(256) void spmm64_fused_kernel(
    const int* __restrict__ rp, const int* __restrict__ scol,
    const float* __restrict__ sval, const float* __restrict__ sup,
    const float* __restrict__ bias, float* __restrict__ z,
    float* __restrict__ part, int M) {
  int w = threadIdx.x >> 6, lane = threadIdx.x & 63;
  float b = bias[lane];
  float cs = 0.f;
  for (int r = blockIdx.x * 4 + w; r < M; r += gridDim.x * 4) {
    int j0 = rp[r], j1 = rp[r + 1];
    float a = 0.f;
    int j = j0;
    for (; j + 4 <= j1; j += 4) {
      int   c0 = scol[j],     c1 = scol[j + 1];
      int   c2 = scol[j + 2], c3 = scol[j + 3];
      float v0 = sval[j],     v1 = sval[j + 1];
      float v2 = sval[j + 2], v3 = sval[j + 3];
      float s0 = sup[(long long)c0 * 64 + lane];
      float s1 = sup[(long long)c1 * 64 + lane];
      float s2 = sup[(long long)c2 * 64 + lane];
      float s3 = sup[(long long)c3 * 64 + lane];
      a += v0 * s0 + v1 * s1 + v2 * s2 + v3 * s3;
    }
    for (; j < j1; ++j)
      a += sval[j] * sup[(long long)scol[j] * 64 + lane];
    float zz = a + b;
    zz = zz > 0.f ? zz : 0.f;
    cs += zz;
    z[(long long)r * 64 + lane] = zz;
  }
  __shared__ float red[4][64];
  red[w][lane] = cs;
  __syncthreads();
  if (w == 0)
    part[(long long)blockIdx.x * 64 + lane] =
        red[0][lane] + red[1][lane] + red[2][lane] + red[3][lane];
}

// ---- reduce NPART partial colsums -> csum[F] (single block, no atomics) ----
__global__ __launch_bounds__(1024) void colsum_reduce_kernel(
    const float* __restrict__ part, float* __restrict__ csum, int F) {
  __shared__ float buf[1024];
  int t = threadIdx.x;
  int S = 1024 / F;                 // slices per feature (8 for F=128, 16 for F=64)
  int f = t % F, s = t / F;
  float a = 0.f;
  for (int bk = s; bk < NPART; bk += S) a += part[(long long)bk * F + f];
  buf[t] = a;
  __syncthreads();
  if (t < F) {
    float r = 0.f;
    for (int s2 = 0; s2 < S; ++s2) r += buf[s2 * F + f];
    csum[f] = r;
  }
}

// ---------------- PairNorm in place: x = (z - colmean) / ||row|| ------------
__global__ __launch_bounds__(256) void pairnorm_kernel(
    float* __restrict__ x, const float* __restrict__ csum, int M, int F) {
  int gid = blockIdx.x * blockDim.x + threadIdx.x;
  int r = gid >> 6;
  int lane = threadIdx.x & 63;
  if (r >= M) return;
  const float invM = 1.0f / (float)M;
  float z0 = x[(long long)r * F + lane] - csum[lane] * invM;
  float z1 = 0.f;
  if (F > 64) z1 = x[(long long)r * F + lane + 64] - csum[lane + 64] * invM;
  float ss = z0 * z0 + z1 * z1;
  for (int o = 32; o > 0; o >>= 1) ss += __shfl_down(ss, o);
  ss = __shfl(ss, 0);
  float rn = 1.0f / sqrtf(EPS_PN + ss);
  x[(long long)r * F + lane] = z0 * rn;
  if (F > 64) x[(long long)r * F + lane + 64] = z1 * rn;
}

// ---------------- decode: sigmoid(dot(x[src], x[dst])) ----------------------
__global__ __launch_bounds__(256) void decode_kernel(
    const int* __restrict__ pos, const int* __restrict__ neg,
    const float* __restrict__ x, float* __restrict__ out,
    int npos, int ntot, int F) {
  int gid = blockIdx.x * blockDim.x + threadIdx.x;
  int e = gid >> 6;
  int lane = threadIdx.x & 63;
  if (e >= ntot) return;
  int src, dst;
  if (e < npos) { src = pos[2 * e];            dst = pos[2 * e + 1]; }
  else          { int q = e - npos; src = neg[2 * q]; dst = neg[2 * q + 1]; }
  float p = x[(long long)src * F + lane] * x[(long long)dst * F + lane];
  for (int o = 32; o > 0; o >>= 1) p += __shfl_down(p, o);
  if (lane == 0) out[e] = 1.0f / (1.0f + expf(-p));
}

extern "C" void kernel_launch(void* const* d_in, const int* in_sizes, int n_in,
                              void* d_out, int out_size, void* d_ws, size_t ws_size,
                              hipStream_t stream) {
  const float* in_feature = (const float*)d_in[0];
  const int*   adj_row    = (const int*)  d_in[1];
  const int*   adj_col    = (const int*)  d_in[2];
  const float* adj_val    = (const float*)d_in[3];
  const int*   pos_ei     = (const int*)  d_in[4];
  const int*   neg_ei     = (const int*)  d_in[5];
  const float* W0 = (const float*)d_in[6];
  const float* b0 = (const float*)d_in[7];
  const float* W1 = (const float*)d_in[8];
  const float* b1 = (const float*)d_in[9];
  const float* W2 = (const float*)d_in[10];
  const float* b2 = (const float*)d_in[11];
  float* out = (float*)d_out;

  char* p = (char*)d_ws;
  auto alloc = [&](size_t bytes) {
    char* r = p;
    p += (bytes + 255) & ~(size_t)255;
    return r;
  };
  const size_t BUF = (size_t)N_NODES * F_HID * sizeof(float);     // 51.2 MB
  float* sup     = (float*)alloc(BUF);
  float* xbuf    = (float*)alloc(BUF);
  short* Wt      = (short*)alloc((size_t)F_HID * 1440 * sizeof(short));
  float* csum    = (float*)alloc(512);
  float* part    = (float*)alloc((size_t)NPART * F_HID * sizeof(float)); // 1 MB
  int*   cnt     = (int*)  alloc((size_t)N_NODES * sizeof(int));
  int*   row_ptr = (int*)  alloc((size_t)(N_NODES + 1) * sizeof(int));
  int*   cursor  = (int*)  alloc((size_t)N_NODES * sizeof(int));
  int*   scol    = (int*)  alloc((size_t)N_NNZ * sizeof(int));
  float* sval    = (float*)alloc((size_t)N_NNZ * sizeof(float));

  // ---- build CSR (once; reused by all 3 layers) ----
  hipMemsetAsync(cnt, 0, (size_t)N_NODES * sizeof(int), stream);
  hist_kernel<<<(N_NNZ + 255) / 256, 256, 0, stream>>>(adj_row, cnt, N_NNZ);
  scan_kernel<<<1, 1024, 0, stream>>>(cnt, row_ptr, cursor, N_NODES, N_NNZ);
  scatter_kernel<<<(N_NNZ + 255) / 256, 256, 0, stream>>>(
      adj_row, adj_col, adj_val, cursor, scol, sval, N_NNZ);

  auto run_layer = [&](const float* xin, int K, const float* W, const float* b,
                       int F) {
    int Kp = ((K + 31) / 32) * 32;
    wcast_kernel<<<(F * Kp + 255) / 256, 256, 0, stream>>>(W, Wt, K, Kp, F);
    if (F == 128) {
      mfma_gemm<128, 128, 2, 2><<<(N_NODES + 127) / 128, 256, 0, stream>>>(
          xin, Wt, sup, N_NODES, K, Kp, F);
      spmm128_fused_kernel<<<NPART, 256, 0, stream>>>(
          row_ptr, scol, sval, sup, b, xbuf, part, N_NODES);
    } else {
      mfma_gemm<128, 64, 2, 2><<<(N_NODES + 127) / 128, 256, 0, stream>>>(
          xin, Wt, sup, N_NODES, K, Kp, F);
      spmm64_fused_kernel<<<NPART, 256, 0, stream>>>(
          row_ptr, scol, sval, sup, b, xbuf, part, N_NODES);
    }
    colsum_reduce_kernel<<<1, 1024, 0, stream>>>(part, csum, F);
    pairnorm_kernel<<<(N_NODES * 64 + 255) / 256, 256, 0, stream>>>(
        xbuf, csum, N_NODES, F);
  };

  run_layer(in_feature, F_IN, W0, b0, F_HID);
  run_layer(xbuf,       F_HID, W1, b1, F_HID);
  run_layer(xbuf,       F_HID, W2, b2, F_OUT);

  decode_kernel<<<((N_POS + N_NEG) * 64 + 255) / 256, 256, 0, stream>>>(
      pos_ei, neg_ei, xbuf, out, N_POS, N_POS + N_NEG, F_OUT);
}

// Round 2
// 1440.158 us; speedup vs baseline: 1.2099x; 1.1587x over previous
//
#include <hip/hip_runtime.h>
#include <math.h>

#define N_NODES 100000
#define N_NNZ   1000000
#define F_IN    1433
#define F_HID   128
#define F_OUT   64
#define N_POS   20000
#define N_NEG   20000
#define EPS_PN  1e-6f
#define NPART   2048        // spmm grid / colsum partial count

typedef float f32x2   __attribute__((ext_vector_type(2)));
typedef float f32x4   __attribute__((ext_vector_type(4)));
typedef float f32x4u  __attribute__((ext_vector_type(4), aligned(4)));
typedef short bf16x8  __attribute__((ext_vector_type(8)));
typedef short bf16x4  __attribute__((ext_vector_type(4)));

__device__ inline short f2bf(float f) {
  union { float f; unsigned u; } x; x.f = f;
  unsigned r = x.u + 0x7fff + ((x.u >> 16) & 1);   // round-to-nearest-even
  return (short)(r >> 16);
}

// ---- W cast+transpose: Wt[n][k] (bf16, Kp-padded) from W[k][n] fp32 --------
__global__ __launch_bounds__(256) void wcast_kernel(
    const float* __restrict__ W, short* __restrict__ Wt, int K, int Kp, int N) {
  int idx = blockIdx.x * blockDim.x + threadIdx.x;
  if (idx >= N * Kp) return;
  int n = idx / Kp, k = idx - n * Kp;
  float v = (k < K) ? W[(long long)k * N + n] : 0.0f;
  Wt[idx] = f2bf(v);
}

// ---- MFMA GEMM, register-prefetch double buffering -------------------------
template<int BMt, int BNt, int WM, int WN>
__global__ __launch_bounds__(256) void mfma_gemm(
    const float* __restrict__ A, const short* __restrict__ Wt,
    float* __restrict__ C, int M, int K, int Kp, int N) {
  constexpr int LD  = 40;                      // LDS row stride in shorts
  constexpr int MI  = BMt / (WM * 16);
  constexpr int NJ  = BNt / (WN * 16);
  constexpr int APF = (BMt * 32) / (256 * 4);  // f32x4 loads of A per thread
  constexpr int WPF = (BNt * 32) / (256 * 8);  // bf16x8 loads of W per thread
  __shared__ __align__(16) short As[BMt * LD];
  __shared__ __align__(16) short Ws[BNt * LD];
  int tid = threadIdx.x;
  int lane = tid & 63, w = tid >> 6;
  int wm = w % WM, wn = w / WM;
  int row0 = blockIdx.x * BMt;
  int ml = lane & 15, kgrp = lane >> 4;

  f32x4 acc[MI][NJ] = {};
  f32x4 pa[APF];
  bf16x8 pw[WPF];

  auto load_a = [&](int k0, f32x4* dst) {
#pragma unroll
    for (int q = 0; q < APF; ++q) {
      int idx = tid + q * 256;
      int r = idx >> 3, k4 = (idx & 7) * 4;
      int gr = row0 + r, gk = k0 + k4;
      f32x4 v = {0.f, 0.f, 0.f, 0.f};
      if (gr < M) {
        if (gk + 3 < K) v = *(const f32x4u*)&A[(long long)gr * K + gk];
        else {
#pragma unroll
          for (int i = 0; i < 4; ++i)
            if (gk + i < K) v[i] = A[(long long)gr * K + gk + i];
        }
      }
      dst[q] = v;
    }
  };
  auto load_w = [&](int k0, bf16x8* dst) {
#pragma unroll
    for (int q = 0; q < WPF; ++q) {
      int idx = tid + q * 256;
      int n = idx >> 2, kk8 = (idx & 3) * 8;
      dst[q] = *(const bf16x8*)&Wt[(long long)n * Kp + k0 + kk8];
    }
  };

  load_a(0, pa);
  load_w(0, pw);

  for (int k0 = 0; k0 < Kp; k0 += 32) {
#pragma unroll
    for (int q = 0; q < APF; ++q) {
      int idx = tid + q * 256;
      int r = idx >> 3, k4 = (idx & 7) * 4;
      bf16x4 b;
#pragma unroll
      for (int i = 0; i < 4; ++i) b[i] = f2bf(pa[q][i]);
      *(bf16x4*)&As[r * LD + k4] = b;
    }
#pragma unroll
    for (int q = 0; q < WPF; ++q) {
      int idx = tid + q * 256;
      int n = idx >> 2, kk8 = (idx & 3) * 8;
      *(bf16x8*)&Ws[n * LD + kk8] = pw[q];
    }
    __syncthreads();

    if (k0 + 32 < Kp) {           // prefetch next tile during MFMAs
      load_a(k0 + 32, pa);
      load_w(k0 + 32, pw);
    }

    bf16x8 af[MI], bfr[NJ];
#pragma unroll
    for (int i = 0; i < MI; ++i)
      af[i] = *(const bf16x8*)&As[(wm * MI * 16 + i * 16 + ml) * LD + kgrp * 8];
#pragma unroll
    for (int j = 0; j < NJ; ++j)
      bfr[j] = *(const bf16x8*)&Ws[(wn * NJ * 16 + j * 16 + ml) * LD + kgrp * 8];
#pragma unroll
    for (int i = 0; i < MI; ++i)
#pragma unroll
      for (int j = 0; j < NJ; ++j)
        acc[i][j] = __builtin_amdgcn_mfma_f32_16x16x32_bf16(
            af[i], bfr[j], acc[i][j], 0, 0, 0);
    __syncthreads();
  }

  // epilogue: D mapping col = lane&15, row = (lane>>4)*4 + rr
#pragma unroll
  for (int i = 0; i < MI; ++i)
#pragma unroll
    for (int j = 0; j < NJ; ++j)
#pragma unroll
      for (int rr = 0; rr < 4; ++rr) {
        int gr = row0 + wm * MI * 16 + i * 16 + kgrp * 4 + rr;
        int gc = wn * NJ * 16 + j * 16 + ml;
        if (gr < M) C[(long long)gr * N + gc] = acc[i][j][rr];
      }
}

// ---------------- CSR build -------------------------------------------------
__global__ __launch_bounds__(256) void hist_kernel(
    const int* __restrict__ row, int* __restrict__ cnt, int nnz) {
  int i = blockIdx.x * blockDim.x + threadIdx.x;
  if (i < nnz) atomicAdd(&cnt[row[i]], 1);
}

// two-level coalesced scan: (1) per-block int4 local exclusive scan + totals
__global__ __launch_bounds__(256) void scan_local_kernel(
    const int* __restrict__ cnt, int* __restrict__ exc,
    int* __restrict__ btot, int n) {
  __shared__ int sh[256];
  int b = blockIdx.x, t = threadIdx.x;
  int base = b * 1024 + t * 4;
  int4 v = {0, 0, 0, 0};
  if (base + 3 < n) v = *(const int4*)&cnt[base];
  else {
    if (base + 0 < n) v.x = cnt[base + 0];
    if (base + 1 < n) v.y = cnt[base + 1];
    if (base + 2 < n) v.z = cnt[base + 2];
    if (base + 3 < n) v.w = cnt[base + 3];
  }
  int s0 = v.x, s1 = s0 + v.y, s2 = s1 + v.z, s3 = s2 + v.w;
  sh[t] = s3;
  __syncthreads();
  for (int off = 1; off < 256; off <<= 1) {
    int x = (t >= off) ? sh[t - off] : 0;
    __syncthreads();
    sh[t] += x;
    __syncthreads();
  }
  int thOff = sh[t] - s3;                  // exclusive offset within block
  if (t == 255) btot[b] = sh[255];
  int4 e;
  e.x = thOff; e.y = thOff + s0; e.z = thOff + s1; e.w = thOff + s2;
  if (base + 3 < n) *(int4*)&exc[base] = e;
  else {
    if (base + 0 < n) exc[base + 0] = e.x;
    if (base + 1 < n) exc[base + 1] = e.y;
    if (base + 2 < n) exc[base + 2] = e.z;
    if (base + 3 < n) exc[base + 3] = e.w;
  }
}

// (2) add block offsets, emit row_ptr + cursor (exc may alias cursor)
__global__ __launch_bounds__(256) void scan_apply_kernel(
    const int* __restrict__ exc, const int* __restrict__ btot,
    int* __restrict__ row_ptr, int* __restrict__ cursor,
    int n, int nnz, int nb) {
  int b = blockIdx.x, t = threadIdx.x;
  int off = 0;
  for (int i = 0; i < b; ++i) off += btot[i];
  int base = b * 1024 + t * 4;
#pragma unroll
  for (int i = 0; i < 4; ++i) {
    int idx = base + i;
    if (idx < n) {
      int val = exc[idx] + off;
      row_ptr[idx] = val;
      cursor[idx]  = val;
    }
  }
  if (b == nb - 1 && t == 0) row_ptr[n] = nnz;
}

// scatter packed (col, val) pairs -> single 8B store per nnz
__global__ __launch_bounds__(256) void scatter_kernel(
    const int* __restrict__ row, const int* __restrict__ col,
    const float* __restrict__ val, int* __restrict__ cursor,
    int2* __restrict__ cv, int nnz) {
  int i = blockIdx.x * blockDim.x + threadIdx.x;
  if (i >= nnz) return;
  int p = atomicAdd(&cursor[row[i]], 1);
  int2 q; q.x = col[i]; q.y = __float_as_int(val[i]);
  cv[p] = q;
}

// ---- CSR SpMM fused bias+relu+colsum-partial, F=128 ------------------------
// 2 rows per wave: half-wave (32 lanes) owns one row, lane q holds feats
// {4q..4q+3} as f32x4 -> 512 B coalesced gather per row, 8 gathers in
// flight per wave. Packed int2 (col,val) stream. Block colsum partial in
// registers -> LDS reduce -> one partial row per block (no atomics).
__global__ __launch_bounds__(256) void spmm128_fused_kernel(
    const int* __restrict__ rp, const int2* __restrict__ cv,
    const float* __restrict__ sup, const float* __restrict__ bias,
    float* __restrict__ z, float* __restrict__ part, int M) {
  int w = threadIdx.x >> 6, lane = threadIdx.x & 63;
  int q = lane & 31, h = lane >> 5;
  int gw = blockIdx.x * 4 + w;
  const int GW = gridDim.x * 4;
  f32x4 b4 = *(const f32x4*)&bias[q * 4];
  f32x4 cs = {0.f, 0.f, 0.f, 0.f};
  for (int r = gw * 2 + h; r < M; r += GW * 2) {
    int j0 = rp[r], j1 = rp[r + 1];
    f32x4 a = {0.f, 0.f, 0.f, 0.f};
    int j = j0;
    for (; j + 4 <= j1; j += 4) {       // 4 gathers in flight per half-wave
      int2 c0 = cv[j],     c1 = cv[j + 1];
      int2 c2 = cv[j + 2], c3 = cv[j + 3];
      f32x4 s0 = *(const f32x4*)&sup[(long long)c0.x * 128 + q * 4];
      f32x4 s1 = *(const f32x4*)&sup[(long long)c1.x * 128 + q * 4];
      f32x4 s2 = *(const f32x4*)&sup[(long long)c2.x * 128 + q * 4];
      f32x4 s3 = *(const f32x4*)&sup[(long long)c3.x * 128 + q * 4];
      a += s0 * __int_as_float(c0.y) + s1 * __int_as_float(c1.y)
         + s2 * __int_as_float(c2.y) + s3 * __int_as_float(c3.y);
    }
    for (; j < j1; ++j) {
      int2 cj = cv[j];
      f32x4 s = *(const f32x4*)&sup[(long long)cj.x * 128 + q * 4];
      a += s * __int_as_float(cj.y);
    }
    f32x4 zz = a + b4;
    zz.x = zz.x > 0.f ? zz.x : 0.f;
    zz.y = zz.y > 0.f ? zz.y : 0.f;
    zz.z = zz.z > 0.f ? zz.z : 0.f;
    zz.w = zz.w > 0.f ? zz.w : 0.f;
    cs += zz;
    *(f32x4*)&z[(long long)r * 128 + q * 4] = zz;
  }
  __shared__ f32x4 red[4][64];
  red[w][lane] = cs;
  __syncthreads();
  if (w == 0 && lane < 32) {
    f32x4 t = red[0][q] + red[1][q] + red[2][q] + red[3][q]
            + red[0][q + 32] + red[1][q + 32] + red[2][q + 32] + red[3][q + 32];
    *(f32x4*)&part[(long long)blockIdx.x * 128 + q * 4] = t;
  }
}

// ---- CSR SpMM fused bias+relu+colsum-partial, F=64 -------------------------
__global__ __launch_bounds__(256) void spmm64_fused_kernel(
    const int* __restrict__ rp, const int2* __restrict__ cv,
    const float* __restrict__ sup, const float* __restrict__ bias,
    float* __restrict__ z, float* __restrict__ part, int M) {
  int w = threadIdx.x >> 6, lane = threadIdx.x & 63;
  int q = lane & 31, h = lane >> 5;
  int gw = blockIdx.x * 4 + w;
  const int GW = gridDim.x * 4;
  f32x2 b2 = *(const f32x2*)&bias[q * 2];
  f32x2 cs = {0.f, 0.f};
  for (int r = gw * 2 + h; r < M; r += GW * 2) {
    int j0 = rp[r], j1 = rp[r + 1];
    f32x2 a = {0.f, 0.f};
    int j = j0;
    for (; j + 4 <= j1; j += 4) {
      int2 c0 = cv[j],     c1 = cv[j + 1];
      int2 c2 = cv[j + 2], c3 = cv[j + 3];
      f32x2 s0 = *(const f32x2*)&sup[(long long)c0.x * 64 + q * 2];
      f32x2 s1 = *(const f32x2*)&sup[(long long)c1.x * 64 + q * 2];
      f32x2 s2 = *(const f32x2*)&sup[(long long)c2.x * 64 + q * 2];
      f32x2 s3 = *(const f32x2*)&sup[(long long)c3.x * 64 + q * 2];
      a += s0 * __int_as_float(c0.y) + s1 * __int_as_float(c1.y)
         + s2 * __int_as_float(c2.y) + s3 * __int_as_float(c3.y);
    }
    for (; j < j1; ++j) {
      int2 cj = cv[j];
      f32x2 s = *(const f32x2*)&sup[(long long)cj.x * 64 + q * 2];
      a += s * __int_as_float(cj.y);
    }
    f32x2 zz = a + b2;
    zz.x = zz.x > 0.f ? zz.x : 0.f;
    zz.y = zz.y > 0.f ? zz.y : 0.f;
    cs += zz;
    *(f32x2*)&z[(long long)r * 64 + q * 2] = zz;
  }
  __shared__ f32x2 red[4][64];
  red[w][lane] = cs;
  __syncthreads();
  if (w == 0 && lane < 32) {
    f32x2 t = red[0][q] + red[1][q] + red[2][q] + red[3][q]
            + red[0][q + 32] + red[1][q + 32] + red[2][q + 32] + red[3][q + 32];
    *(f32x2*)&part[(long long)blockIdx.x * 64 + q * 2] = t;
  }
}

// ---- reduce NPART partial colsums -> csum[F] (single block, no atomics) ----
__global__ __launch_bounds__(1024) void colsum_reduce_kernel(
    const float* __restrict__ part, float* __restrict__ csum, int F) {
  __shared__ float buf[1024];
  int t = threadIdx.x;
  int S = 1024 / F;
  int f = t % F, s = t / F;
  float a = 0.f;
  for (int bk = s; bk < NPART; bk += S) a += part[(long long)bk * F + f];
  buf[t] = a;
  __syncthreads();
  if (t < F) {
    float r = 0.f;
    for (int s2 = 0; s2 < S; ++s2) r += buf[s2 * F + f];
    csum[f] = r;
  }
}

// ---------------- PairNorm in place: x = (z - colmean) / ||row|| ------------
__global__ __launch_bounds__(256) void pairnorm_kernel(
    float* __restrict__ x, const float* __restrict__ csum, int M, int F) {
  int gid = blockIdx.x * blockDim.x + threadIdx.x;
  int r = gid >> 6;
  int lane = threadIdx.x & 63;
  if (r >= M) return;
  const float invM = 1.0f / (float)M;
  float z0 = x[(long long)r * F + lane] - csum[lane] * invM;
  float z1 = 0.f;
  if (F > 64) z1 = x[(long long)r * F + lane + 64] - csum[lane + 64] * invM;
  float ss = z0 * z0 + z1 * z1;
  for (int o = 32; o > 0; o >>= 1) ss += __shfl_down(ss, o);
  ss = __shfl(ss, 0);
  float rn = 1.0f / sqrtf(EPS_PN + ss);
  x[(long long)r * F + lane] = z0 * rn;
  if (F > 64) x[(long long)r * F + lane + 64] = z1 * rn;
}

// ---------------- decode: sigmoid(dot(x[src], x[dst])) ----------------------
__global__ __launch_bounds__(256) void decode_kernel(
    const int* __restrict__ pos, const int* __restrict__ neg,
    const float* __restrict__ x, float* __restrict__ out,
    int npos, int ntot, int F) {
  int gid = blockIdx.x * blockDim.x + threadIdx.x;
  int e = gid >> 6;
  int lane = threadIdx.x & 63;
  if (e >= ntot) return;
  int src, dst;
  if (e < npos) { src = pos[2 * e];            dst = pos[2 * e + 1]; }
  else          { int q = e - npos; src = neg[2 * q]; dst = neg[2 * q + 1]; }
  float p = x[(long long)src * F + lane] * x[(long long)dst * F + lane];
  for (int o = 32; o > 0; o >>= 1) p += __shfl_down(p, o);
  if (lane == 0) out[e] = 1.0f / (1.0f + expf(-p));
}

extern "C" void kernel_launch(void* const* d_in, const int* in_sizes, int n_in,
                              void* d_out, int out_size, void* d_ws, size_t ws_size,
                              hipStream_t stream) {
  const float* in_feature = (const float*)d_in[0];
  const int*   adj_row    = (const int*)  d_in[1];
  const int*   adj_col    = (const int*)  d_in[2];
  const float* adj_val    = (const float*)d_in[3];
  const int*   pos_ei     = (const int*)  d_in[4];
  const int*   neg_ei     = (const int*)  d_in[5];
  const float* W0 = (const float*)d_in[6];
  const float* b0 = (const float*)d_in[7];
  const float* W1 = (const float*)d_in[8];
  const float* b1 = (const float*)d_in[9];
  const float* W2 = (const float*)d_in[10];
  const float* b2 = (const float*)d_in[11];
  float* out = (float*)d_out;

  char* p = (char*)d_ws;
  auto alloc = [&](size_t bytes) {
    char* r = p;
    p += (bytes + 255) & ~(size_t)255;
    return r;
  };
  const size_t BUF = (size_t)N_NODES * F_HID * sizeof(float);     // 51.2 MB
  float* sup     = (float*)alloc(BUF);
  float* xbuf    = (float*)alloc(BUF);
  short* Wt      = (short*)alloc((size_t)F_HID * 1440 * sizeof(short));
  float* csum    = (float*)alloc(512);
  float* part    = (float*)alloc((size_t)NPART * F_HID * sizeof(float)); // 1 MB
  int*   cnt     = (int*)  alloc((size_t)N_NODES * sizeof(int));
  int*   btot    = (int*)  alloc(1024);
  int*   row_ptr = (int*)  alloc((size_t)(N_NODES + 1) * sizeof(int));
  int*   cursor  = (int*)  alloc((size_t)N_NODES * sizeof(int));
  int2*  cv      = (int2*) alloc((size_t)N_NNZ * sizeof(int2));

  const int NB = (N_NODES + 1023) / 1024;

  // ---- build CSR (once; reused by all 3 layers) ----
  hipMemsetAsync(cnt, 0, (size_t)N_NODES * sizeof(int), stream);
  hist_kernel<<<(N_NNZ + 255) / 256, 256, 0, stream>>>(adj_row, cnt, N_NNZ);
  scan_local_kernel<<<NB, 256, 0, stream>>>(cnt, cursor, btot, N_NODES);
  scan_apply_kernel<<<NB, 256, 0, stream>>>(cursor, btot, row_ptr, cursor,
                                            N_NODES, N_NNZ, NB);
  scatter_kernel<<<(N_NNZ + 255) / 256, 256, 0, stream>>>(
      adj_row, adj_col, adj_val, cursor, cv, N_NNZ);

  auto run_layer = [&](const float* xin, int K, const float* W, const float* b,
                       int F) {
    int Kp = ((K + 31) / 32) * 32;
    wcast_kernel<<<(F * Kp + 255) / 256, 256, 0, stream>>>(W, Wt, K, Kp, F);
    if (F == 128) {
      mfma_gemm<128, 128, 2, 2><<<(N_NODES + 127) / 128, 256, 0, stream>>>(
          xin, Wt, sup, N_NODES, K, Kp, F);
      spmm128_fused_kernel<<<NPART, 256, 0, stream>>>(
          row_ptr, cv, sup, b, xbuf, part, N_NODES);
    } else {
      mfma_gemm<128, 64, 2, 2><<<(N_NODES + 127) / 128, 256, 0, stream>>>(
          xin, Wt, sup, N_NODES, K, Kp, F);
      spmm64_fused_kernel<<<NPART, 256, 0, stream>>>(
          row_ptr, cv, sup, b, xbuf, part, N_NODES);
    }
    colsum_reduce_kernel<<<1, 1024, 0, stream>>>(part, csum, F);
    pairnorm_kernel<<<(N_NODES * 64 + 255) / 256, 256, 0, stream>>>(
        xbuf, csum, N_NODES, F);
  };

  run_layer(in_feature, F_IN, W0, b0, F_HID);
  run_layer(xbuf,       F_HID, W1, b1, F_HID);
  run_layer(xbuf,       F_HID, W2, b2, F_OUT);

  decode_kernel<<<((N_POS + N_NEG) * 64 + 255) / 256, 256, 0, stream>>>(
      pos_ei, neg_ei, xbuf, out, N_POS, N_POS + N_NEG, F_OUT);
}